// Round 2
// baseline (2794.055 us; speedup 1.0000x reference)
//
#include <hip/hip_runtime.h>

// CommAgent fully-fused pipeline for MI355X (gfx950), bf16 MFMA throughout.
// ROWS=65536, INPUT=512, H=256, NA=32, 4 comm steps, N_ACTIONS=16.
// One block = 64 rows = 2 complete agent groups -> whole pipeline fused,
// h never leaves LDS between stages.

typedef __attribute__((ext_vector_type(8))) short frag8;   // 8 bf16 (4 VGPRs)
typedef __attribute__((ext_vector_type(4))) float facc4;   // MFMA C/D

__device__ __forceinline__ unsigned short f2bf(float f){
    unsigned u = __builtin_bit_cast(unsigned, f);
    u += 0x7fffu + ((u >> 16) & 1u);            // RNE
    return (unsigned short)(u >> 16);
}
__device__ __forceinline__ float bf2f(unsigned short h){
    unsigned u = ((unsigned)h) << 16;
    return __builtin_bit_cast(float, u);
}
__device__ __forceinline__ unsigned pk2(float a, float b){
    return (unsigned)f2bf(a) | ((unsigned)f2bf(b) << 16);
}
__device__ __forceinline__ float sigm(float x){ return 1.0f / (1.0f + __expf(-x)); }
__device__ __forceinline__ float tanh_(float x){ return 2.0f / (1.0f + __expf(-2.0f*x)) - 1.0f; }

__device__ __forceinline__ facc4 mfma16(frag8 a, frag8 b, facc4 c){
    return __builtin_amdgcn_mfma_f32_16x16x32_bf16(a, b, c, 0, 0, 0);
}
__device__ __forceinline__ void zacc(facc4* p, int n){
    #pragma unroll
    for (int i = 0; i < 16; ++i) { if (i < n) p[i] = (facc4){0.f,0.f,0.f,0.f}; }
}
// XOR-swizzled LDS index (16B-chunk granularity), ld in shorts
__device__ __forceinline__ int swz(int row, int col, int ld){
    return row*ld + ((((col >> 3) ^ (row & 7)) << 3) | (col & 7));
}

// acc[NMB][4] += A_lds(rows mb0*16..) @ W[nbase..nbase+255, K]^T
// wave owns n-tiles 4w..4w+3.  K compile-time -> fully unrolled, loads hoisted.
template<int NMB, int K, int LD, int WK>
__device__ __forceinline__ void gemm_bt(facc4 acc[NMB][4],
    const unsigned short* Al, const int mb0,
    const unsigned short* __restrict__ W, const int nbase)
{
    const int lane = threadIdx.x & 63;
    const int wave = threadIdx.x >> 6;
    const int r16  = lane & 15;
    const int q8   = (lane >> 4) << 3;
    int rowbase[NMB], rx[NMB];
    #pragma unroll
    for (int mb = 0; mb < NMB; ++mb){
        int row = (mb0 + mb)*16 + r16;
        rowbase[mb] = row * LD;
        rx[mb] = row & 7;
    }
    const unsigned short* wbase = W + (size_t)(nbase + wave*64 + r16) * WK + q8;
    #pragma unroll
    for (int k0 = 0; k0 < K; k0 += 32){
        const int c8 = (k0 + q8) >> 3;
        frag8 a[NMB];
        #pragma unroll
        for (int mb = 0; mb < NMB; ++mb)
            a[mb] = *(const frag8*)(Al + rowbase[mb] + ((c8 ^ rx[mb]) << 3));
        #pragma unroll
        for (int tt = 0; tt < 4; ++tt){
            frag8 b = *(const frag8*)(wbase + tt*16*WK + k0);
            #pragma unroll
            for (int mb = 0; mb < NMB; ++mb)
                acc[mb][tt] = mfma16(a[mb], b, acc[mb][tt]);
        }
    }
}

// stage 64 rows x 256 f32 -> bf16 swizzled LDS (ld=256)
__device__ __forceinline__ void stage_f32(unsigned short* dst, const float* src){
    int t = threadIdx.x;
    #pragma unroll
    for (int it = 0; it < 8; ++it){
        int idx = it*256 + t;
        int row = idx >> 5, ch = idx & 31;
        const float4* s = (const float4*)(src + (size_t)row*256 + (ch << 3));
        float4 a = s[0], b = s[1];
        uint4 o; o.x = pk2(a.x,a.y); o.y = pk2(a.z,a.w); o.z = pk2(b.x,b.y); o.w = pk2(b.z,b.w);
        *(uint4*)(dst + row*256 + ((ch ^ (row & 7)) << 3)) = o;
    }
}

// ---- weight f32->bf16 conversion (segments packed contiguously in ws) ----
__global__ void k_prep(const float* __restrict__ s0, const float* __restrict__ s1,
                       const float* __restrict__ s2, const float* __restrict__ s3,
                       const float* __restrict__ s4, const float* __restrict__ s5,
                       unsigned short* __restrict__ dst)
{
    int idx = (blockIdx.x*256 + threadIdx.x) * 4;   // 921600 elems total
    const float* src;
    if      (idx < 131072) src = s0 + idx;
    else if (idx < 327680) src = s1 + (idx - 131072);
    else if (idx < 524288) src = s2 + (idx - 327680);
    else if (idx < 720896) src = s3 + (idx - 524288);
    else if (idx < 917504) src = s4 + (idx - 720896);
    else                   src = s5 + (idx - 917504);
    float4 v = *(const float4*)src;
    uint2 o; o.x = pk2(v.x, v.y); o.y = pk2(v.z, v.w);
    *(uint2*)(dst + idx) = o;
}

// GRU with output packed to registers.  gate order r -> n -> z (each weight
// slice read exactly once from L2).  Blend: h = (1-z)*n + z*ghA  (ghA is the
// reference gru_cell's second arg).
__device__ __forceinline__ void gru_fused(
    const unsigned short* giA, const unsigned short* ghA,   // LDS ld=256 swizzled
    const unsigned short* __restrict__ Wih, const unsigned short* __restrict__ Whh,
    const float* __restrict__ bih, const float* __restrict__ bhh,
    unsigned hpk[4][4][2])
{
    const int lane = threadIdx.x & 63, wave = threadIdx.x >> 6;
    const int r16 = lane & 15, q4 = (lane >> 4) << 2;
    unsigned rp[4][4][2], np[4][4][2];
    {   // ---- r gate ----
        facc4 acc[4][4];
        zacc(&acc[0][0], 16);
        gemm_bt<4,256,256,256>(acc, giA, 0, Wih, 0);
        gemm_bt<4,256,256,256>(acc, ghA, 0, Whh, 0);
        #pragma unroll
        for (int tt = 0; tt < 4; ++tt){
            int col = wave*64 + tt*16 + r16;
            float bs = bih[col] + bhh[col];
            #pragma unroll
            for (int mb = 0; mb < 4; ++mb){
                rp[mb][tt][0] = pk2(sigm(acc[mb][tt][0]+bs), sigm(acc[mb][tt][1]+bs));
                rp[mb][tt][1] = pk2(sigm(acc[mb][tt][2]+bs), sigm(acc[mb][tt][3]+bs));
            }
        }
    }
    {   // ---- n gate (needs r) ----
        facc4 ai[4][4], ah[4][4];
        zacc(&ai[0][0], 16);
        zacc(&ah[0][0], 16);
        gemm_bt<4,256,256,256>(ai, giA, 0, Wih, 512);
        gemm_bt<4,256,256,256>(ah, ghA, 0, Whh, 512);
        #pragma unroll
        for (int tt = 0; tt < 4; ++tt){
            int col = wave*64 + tt*16 + r16;
            float bi = bih[512+col], bh = bhh[512+col];
            #pragma unroll
            for (int mb = 0; mb < 4; ++mb){
                float r0 = bf2f((unsigned short)(rp[mb][tt][0] & 0xffff));
                float r1 = bf2f((unsigned short)(rp[mb][tt][0] >> 16));
                float r2 = bf2f((unsigned short)(rp[mb][tt][1] & 0xffff));
                float r3 = bf2f((unsigned short)(rp[mb][tt][1] >> 16));
                float n0 = tanh_(ai[mb][tt][0] + bi + r0*(ah[mb][tt][0] + bh));
                float n1 = tanh_(ai[mb][tt][1] + bi + r1*(ah[mb][tt][1] + bh));
                float n2 = tanh_(ai[mb][tt][2] + bi + r2*(ah[mb][tt][2] + bh));
                float n3 = tanh_(ai[mb][tt][3] + bi + r3*(ah[mb][tt][3] + bh));
                np[mb][tt][0] = pk2(n0, n1);
                np[mb][tt][1] = pk2(n2, n3);
            }
        }
    }
    {   // ---- z gate + blend ----
        facc4 acc[4][4];
        zacc(&acc[0][0], 16);
        gemm_bt<4,256,256,256>(acc, giA, 0, Wih, 256);
        gemm_bt<4,256,256,256>(acc, ghA, 0, Whh, 256);
        #pragma unroll
        for (int tt = 0; tt < 4; ++tt){
            int col = wave*64 + tt*16 + r16;
            float bs = bih[256+col] + bhh[256+col];
            #pragma unroll
            for (int mb = 0; mb < 4; ++mb){
                #pragma unroll
                for (int k = 0; k < 4; ++k){
                    float z = sigm(acc[mb][tt][k] + bs);
                    float n = bf2f((unsigned short)(np[mb][tt][k>>1] >> ((k&1)*16)));
                    float hp = bf2f(ghA[swz(mb*16 + q4 + k, col, 256)]);
                    float h = (1.f - z)*n + z*hp;
                    if (k & 1) hpk[mb][tt][k>>1] |= ((unsigned)f2bf(h)) << 16;
                    else       hpk[mb][tt][k>>1]  = (unsigned)f2bf(h);
                }
            }
        }
    }
}

__global__ __launch_bounds__(256,2) void k_fused(
    const float* __restrict__ inputs, const float* __restrict__ h0,
    const unsigned short* __restrict__ W1c, const float* __restrict__ b1,
    const unsigned short* __restrict__ rWih, const unsigned short* __restrict__ rWhh,
    const float* __restrict__ rbih, const float* __restrict__ rbhh,
    const unsigned short* __restrict__ cWih, const unsigned short* __restrict__ cWhh,
    const float* __restrict__ cbih, const float* __restrict__ cbhh,
    const unsigned short* __restrict__ W2c, const float* __restrict__ b2,
    float* __restrict__ qout, float* __restrict__ hrnn)
{
    __shared__ unsigned short sm[64*512];      // 64 KB: input tile, then bufA|bufB
    __shared__ unsigned short NBs[64*32];      // 4 KB neighbor matrix
    __shared__ float invn[64];
    unsigned short* bufA = sm;                 // 32 KB  (x, then c)
    unsigned short* bufB = sm + 64*256;        // 32 KB  (h)
    const int base = blockIdx.x * 64;
    const int lane = threadIdx.x & 63, wave = threadIdx.x >> 6;
    const int r16 = lane & 15, q8 = (lane>>4)<<3, q4 = (lane>>4)<<2;

    // ---- stage input tile 64x512 f32->bf16 swizzled (ld=512) ----
    {
        const float* src = inputs + (size_t)base * 512;
        int t = threadIdx.x;
        #pragma unroll
        for (int it = 0; it < 16; ++it){
            int idx = it*256 + t;
            int row = idx >> 6, ch = idx & 63;
            const float4* s = (const float4*)(src + (size_t)row*512 + (ch << 3));
            float4 a = s[0], c = s[1];
            uint4 o; o.x = pk2(a.x,a.y); o.y = pk2(a.z,a.w); o.z = pk2(c.x,c.y); o.w = pk2(c.z,c.w);
            *(uint4*)(sm + row*512 + ((ch ^ (row & 7)) << 3)) = o;
        }
    }
    __syncthreads();
    // ---- neighbor matrix + 1/n into LDS (cols 260+8k of obs) ----
    if (threadIdx.x < 64){
        int row = threadIdx.x;
        int i = (base + row) & 31;
        int rx = row & 7;
        float s = 0.f;
        NBs[row*32 + i] = 0;
        #pragma unroll
        for (int k = 0; k < 31; ++k){
            unsigned short v = sm[row*512 + ((((32 + k) ^ rx) << 3) | 4)];
            s += bf2f(v);
            NBs[row*32 + k + (k >= i)] = v;
        }
        invn[row] = 1.0f / s;
    }
    // ---- x = relu(in @ W1^T + b1), into registers ----
    facc4 xacc[4][4];
    zacc(&xacc[0][0], 16);
    gemm_bt<4,512,512,512>(xacc, sm, 0, W1c, 0);
    __syncthreads();                       // input tile reads done
    // ---- x -> bufA (bf16 swizzled); h0 -> bufB ----
    #pragma unroll
    for (int tt = 0; tt < 4; ++tt){
        int col = wave*64 + tt*16 + r16;
        float bias = b1[col];
        #pragma unroll
        for (int mb = 0; mb < 4; ++mb){
            #pragma unroll
            for (int k = 0; k < 4; ++k){
                float v = fmaxf(xacc[mb][tt][k] + bias, 0.f);
                bufA[swz(mb*16 + q4 + k, col, 256)] = f2bf(v);
            }
        }
    }
    stage_f32(bufB, h0 + (size_t)base*256);
    __syncthreads();

    // ---- rnn GRU: h1 = GRU(x, h0) ----
    unsigned hpk[4][4][2];
    gru_fused(bufA, bufB, rWih, rWhh, rbih, rbhh, hpk);
    __syncthreads();                       // bufA/bufB reads done
    #pragma unroll
    for (int tt = 0; tt < 4; ++tt){
        int col = wave*64 + tt*16 + r16;
        #pragma unroll
        for (int mb = 0; mb < 4; ++mb){
            #pragma unroll
            for (int k = 0; k < 4; ++k)
                bufB[swz(mb*16 + q4 + k, col, 256)] =
                    (unsigned short)(hpk[mb][tt][k>>1] >> ((k&1)*16));
        }
    }
    __syncthreads();
    // ---- hrnn: coalesced f32 write from bufB ----
    {
        int t = threadIdx.x;
        #pragma unroll
        for (int it = 0; it < 8; ++it){
            int idx = it*256 + t;
            int row = idx >> 5, ch = idx & 31;
            uint4 v = *(const uint4*)(bufB + row*256 + ((ch ^ (row & 7)) << 3));
            float* dst = hrnn + (size_t)(base + row)*256 + (ch << 3);
            float4 f0, f1;
            f0.x = bf2f((unsigned short)(v.x & 0xffff)); f0.y = bf2f((unsigned short)(v.x >> 16));
            f0.z = bf2f((unsigned short)(v.y & 0xffff)); f0.w = bf2f((unsigned short)(v.y >> 16));
            f1.x = bf2f((unsigned short)(v.z & 0xffff)); f1.y = bf2f((unsigned short)(v.z >> 16));
            f1.z = bf2f((unsigned short)(v.w & 0xffff)); f1.w = bf2f((unsigned short)(v.w >> 16));
            *(float4*)dst = f0;
            *(float4*)(dst + 4) = f1;
        }
    }
    // ---- 4 comm steps (not unrolled: I-cache) ----
    for (int step = 0; step < 4; ++step){
        // c = (NB @ h) * invn  -> bufA ; per 32-row group, K=32
        facc4 cacc[4][4];
        zacc(&cacc[0][0], 16);
        frag8 a[4];
        #pragma unroll
        for (int mb = 0; mb < 4; ++mb)
            a[mb] = *(const frag8*)(NBs + (mb*16 + r16)*32 + q8);
        #pragma unroll
        for (int tt = 0; tt < 4; ++tt){
            int col = wave*64 + tt*16 + r16;
            int cc = col >> 3, c7 = col & 7;
            union { frag8 v; unsigned short u[8]; } b0l, b1l;
            #pragma unroll
            for (int j = 0; j < 8; ++j){
                int k0r = q8 + j;          // group 0: rows 0..31
                int k1r = 32 + q8 + j;     // group 1: rows 32..63
                b0l.u[j] = bufB[k0r*256 + (((cc ^ (k0r & 7)) << 3) | c7)];
                b1l.u[j] = bufB[k1r*256 + (((cc ^ (k1r & 7)) << 3) | c7)];
            }
            cacc[0][tt] = mfma16(a[0], b0l.v, cacc[0][tt]);
            cacc[1][tt] = mfma16(a[1], b0l.v, cacc[1][tt]);
            cacc[2][tt] = mfma16(a[2], b1l.v, cacc[2][tt]);
            cacc[3][tt] = mfma16(a[3], b1l.v, cacc[3][tt]);
        }
        #pragma unroll
        for (int mb = 0; mb < 4; ++mb){
            #pragma unroll
            for (int k = 0; k < 4; ++k){
                int rloc = mb*16 + q4 + k;
                float inv = invn[rloc];
                #pragma unroll
                for (int tt = 0; tt < 4; ++tt){
                    int col = wave*64 + tt*16 + r16;
                    bufA[swz(rloc, col, 256)] = f2bf(cacc[mb][tt][k] * inv);
                }
            }
        }
        __syncthreads();
        // h = GRU(h, c): gi from h (bufB), gh/blend from c (bufA)
        gru_fused(bufB, bufA, cWih, cWhh, cbih, cbhh, hpk);
        __syncthreads();
        #pragma unroll
        for (int tt = 0; tt < 4; ++tt){
            int col = wave*64 + tt*16 + r16;
            #pragma unroll
            for (int mb = 0; mb < 4; ++mb){
                #pragma unroll
                for (int k = 0; k < 4; ++k)
                    bufB[swz(mb*16 + q4 + k, col, 256)] =
                        (unsigned short)(hpk[mb][tt][k>>1] >> ((k&1)*16));
            }
        }
        __syncthreads();
    }
    // ---- q = h @ W2^T + b2 (one 16-col n-tile, wave per 16 rows) ----
    {
        facc4 acc = (facc4){0.f,0.f,0.f,0.f};
        int row = wave*16 + r16;
        const unsigned short* brow = W2c + (size_t)r16*256 + q8;
        #pragma unroll
        for (int k0 = 0; k0 < 256; k0 += 32){
            int c8 = (k0 + q8) >> 3;
            frag8 a = *(const frag8*)(bufB + row*256 + ((c8 ^ (row & 7)) << 3));
            frag8 b = *(const frag8*)(brow + k0);
            acc = mfma16(a, b, acc);
        }
        float bias = b2[r16];
        #pragma unroll
        for (int k = 0; k < 4; ++k){
            int grow = base + wave*16 + q4 + k;
            qout[(size_t)grow*16 + r16] = acc[k] + bias;
        }
    }
}

extern "C" void kernel_launch(void* const* d_in, const int* in_sizes, int n_in,
                              void* d_out, int out_size, void* d_ws, size_t ws_size,
                              hipStream_t stream)
{
    const float* inputs = (const float*)d_in[0];
    const float* h0     = (const float*)d_in[1];
    const float* W1     = (const float*)d_in[2];
    const float* b1     = (const float*)d_in[3];
    const float* rWih   = (const float*)d_in[4];
    const float* rWhh   = (const float*)d_in[5];
    const float* rbih   = (const float*)d_in[6];
    const float* rbhh   = (const float*)d_in[7];
    const float* cWih   = (const float*)d_in[8];
    const float* cWhh   = (const float*)d_in[9];
    const float* cbih   = (const float*)d_in[10];
    const float* cbhh   = (const float*)d_in[11];
    const float* W2     = (const float*)d_in[12];
    const float* b2     = (const float*)d_in[13];

    float* qout = (float*)d_out;                    // 65536 x 16
    float* hrnn = qout + (size_t)65536*16;          // 65536 x 256

    // ws: bf16 weights packed contiguously
    unsigned short* wsb  = (unsigned short*)d_ws;
    unsigned short* W1c   = wsb;                    // 256x512
    unsigned short* rWihc = wsb + 131072;           // 768x256
    unsigned short* rWhhc = wsb + 327680;           // 768x256
    unsigned short* cWihc = wsb + 524288;           // 768x256
    unsigned short* cWhhc = wsb + 720896;           // 768x256
    unsigned short* W2c   = wsb + 917504;           // 16x256

    dim3 blk(256);
    k_prep <<<900,  blk, 0, stream>>>(W1, rWih, rWhh, cWih, cWhh, W2, wsb);
    k_fused<<<1024, blk, 0, stream>>>(inputs, h0, W1c, b1, rWihc, rWhhc, rbih, rbhh,
                                      cWihc, cWhhc, cbih, cbhh, W2c, b2, qout, hrnn);
}

// Round 3
// 2728.207 us; speedup vs baseline: 1.0241x; 1.0241x over previous
//
#include <hip/hip_runtime.h>

// CommAgent fully-fused pipeline for MI355X (gfx950), bf16 MFMA throughout.
// ROWS=65536, INPUT=512, H=256, NA=32, 4 comm steps, N_ACTIONS=16.
// One block = 64 rows = 2 complete agent groups; h lives in LDS end-to-end.
// Round 3: spill-free GRU phases, fragment-packed weights, non-temporal
// streaming so weights stay L2-resident.

typedef __attribute__((ext_vector_type(8))) short frag8;   // 8 bf16 (4 VGPRs)
typedef __attribute__((ext_vector_type(4))) float facc4;   // MFMA C/D
typedef __attribute__((ext_vector_type(4))) float f32x4;
typedef __attribute__((ext_vector_type(4))) unsigned u32x4;

__device__ __forceinline__ unsigned short f2bf(float f){
    unsigned u = __builtin_bit_cast(unsigned, f);
    u += 0x7fffu + ((u >> 16) & 1u);            // RNE
    return (unsigned short)(u >> 16);
}
__device__ __forceinline__ float bf2f(unsigned short h){
    unsigned u = ((unsigned)h) << 16;
    return __builtin_bit_cast(float, u);
}
__device__ __forceinline__ unsigned pk2(float a, float b){
    return (unsigned)f2bf(a) | ((unsigned)f2bf(b) << 16);
}
__device__ __forceinline__ float sigm(float x){ return 1.0f / (1.0f + __expf(-x)); }
__device__ __forceinline__ float tanh_(float x){ return 2.0f / (1.0f + __expf(-2.0f*x)) - 1.0f; }

__device__ __forceinline__ facc4 mfma16(frag8 a, frag8 b, facc4 c){
    return __builtin_amdgcn_mfma_f32_16x16x32_bf16(a, b, c, 0, 0, 0);
}
__device__ __forceinline__ void zacc16(facc4 (&p)[4][4]){
    #pragma unroll
    for (int i = 0; i < 4; ++i)
        #pragma unroll
        for (int j = 0; j < 4; ++j) p[i][j] = (facc4){0.f,0.f,0.f,0.f};
}
// XOR-swizzled LDS index (16B-chunk granularity), ld in shorts
__device__ __forceinline__ int swz(int row, int col, int ld){
    return row*ld + ((((col >> 3) ^ (row & 7)) << 3) | (col & 7));
}

// acc[4][4] += A_lds(rows 0..63) @ Wslice^T for this wave's 64-col strip.
// Wp is fragment-packed: frag8 at ((nt*WKC + kc)*64 + lane)*8, nt = n/16.
template<int K, int LD, int WKC>
__device__ __forceinline__ void gemm_bt(facc4 (&acc)[4][4],
    const unsigned short* Al, const unsigned short* __restrict__ Wp,
    const int ntile0)
{
    const int lane = threadIdx.x & 63;
    const int wave = threadIdx.x >> 6;
    const int r16  = lane & 15;
    const int q8   = (lane >> 4) << 3;
    int rowbase[4], rx[4];
    #pragma unroll
    for (int mb = 0; mb < 4; ++mb){
        int row = mb*16 + r16;
        rowbase[mb] = row * LD;
        rx[mb] = row & 7;
    }
    const unsigned short* wl = Wp + ((size_t)(ntile0 + wave*4) * WKC * 64 + lane) * 8;
    #pragma unroll
    for (int kc = 0; kc < K/32; ++kc){
        const int c8 = kc*4 + (q8 >> 3);
        frag8 a[4];
        #pragma unroll
        for (int mb = 0; mb < 4; ++mb)
            a[mb] = *(const frag8*)(Al + rowbase[mb] + ((c8 ^ rx[mb]) << 3));
        #pragma unroll
        for (int tt = 0; tt < 4; ++tt){
            frag8 b = *(const frag8*)(wl + (size_t)(tt*WKC + kc)*512);
            #pragma unroll
            for (int mb = 0; mb < 4; ++mb)
                acc[mb][tt] = mfma16(a[mb], b, acc[mb][tt]);
        }
    }
}

// stage 64 rows x 256 f32 -> bf16 swizzled LDS (ld=256), non-temporal reads
__device__ __forceinline__ void stage_f32(unsigned short* dst, const float* src){
    int t = threadIdx.x;
    #pragma unroll
    for (int it = 0; it < 8; ++it){
        int idx = it*256 + t;
        int row = idx >> 5, ch = idx & 31;
        const f32x4* s = (const f32x4*)(src + (size_t)row*256 + (ch << 3));
        f32x4 a = __builtin_nontemporal_load(s);
        f32x4 b = __builtin_nontemporal_load(s + 1);
        u32x4 o; o.x = pk2(a.x,a.y); o.y = pk2(a.z,a.w); o.z = pk2(b.x,b.y); o.w = pk2(b.z,b.w);
        *(u32x4*)(dst + row*256 + ((ch ^ (row & 7)) << 3)) = o;
    }
}

// ---- weight f32 -> bf16 fragment-packed layout ----
// frag index f covers: W1(16384) rW ih/hh(24576 ea) cWih/hh(24576 ea) W2(512)
__global__ void k_prep(const float* __restrict__ s0, const float* __restrict__ s1,
                       const float* __restrict__ s2, const float* __restrict__ s3,
                       const float* __restrict__ s4, const float* __restrict__ s5,
                       unsigned short* __restrict__ dst)
{
    int f = blockIdx.x*256 + threadIdx.x;       // 115200 total
    const float* src; int K, fl;
    if      (f < 16384)  { src = s0; K = 512; fl = f; }
    else if (f < 40960)  { src = s1; K = 256; fl = f - 16384; }
    else if (f < 65536)  { src = s2; K = 256; fl = f - 40960; }
    else if (f < 90112)  { src = s3; K = 256; fl = f - 65536; }
    else if (f < 114688) { src = s4; K = 256; fl = f - 90112; }
    else                 { src = s5; K = 256; fl = f - 114688; }
    const int KC = K >> 5;
    int lane = fl & 63;
    int kc   = (fl >> 6) % KC;
    int nt   = (fl >> 6) / KC;
    int row  = nt*16 + (lane & 15);
    int col  = kc*32 + ((lane >> 4) << 3);
    const f32x4* p = (const f32x4*)(src + (size_t)row*K + col);
    f32x4 a = __builtin_nontemporal_load(p);
    f32x4 b = __builtin_nontemporal_load(p + 1);
    u32x4 o; o.x = pk2(a.x,a.y); o.y = pk2(a.z,a.w); o.z = pk2(b.x,b.y); o.w = pk2(b.z,b.w);
    *(u32x4*)(dst + (size_t)f*8) = o;
}

// GRU, spill-free: gate order r -> n(ah then ai, single acc set) -> z+blend.
// h_new = (1-z)*n + z*ghA   (ghA = reference gru_cell's 2nd arg)
__device__ __forceinline__ void gru_fused(
    const unsigned short* giA, const unsigned short* ghA,   // LDS ld=256 swizzled
    const unsigned short* __restrict__ Wih, const unsigned short* __restrict__ Whh,
    const float* __restrict__ bih, const float* __restrict__ bhh,
    unsigned (&hpk)[4][4][2])
{
    const int lane = threadIdx.x & 63, wave = threadIdx.x >> 6;
    const int r16 = lane & 15, q4 = (lane >> 4) << 2;
    unsigned rp[4][4][2];                      // r, reused in-place as r*(ah+bh)
    {   // ---- r gate ----
        facc4 acc[4][4];
        zacc16(acc);
        gemm_bt<256,256,8>(acc, giA, Wih, 0);
        gemm_bt<256,256,8>(acc, ghA, Whh, 0);
        #pragma unroll
        for (int tt = 0; tt < 4; ++tt){
            int col = wave*64 + tt*16 + r16;
            float bs = bih[col] + bhh[col];
            #pragma unroll
            for (int mb = 0; mb < 4; ++mb){
                rp[mb][tt][0] = pk2(sigm(acc[mb][tt][0]+bs), sigm(acc[mb][tt][1]+bs));
                rp[mb][tt][1] = pk2(sigm(acc[mb][tt][2]+bs), sigm(acc[mb][tt][3]+bs));
            }
        }
    }
    unsigned np[4][4][2];
    {   // ---- n gate: ah half, fold r in place, then ai half ----
        facc4 acc[4][4];
        zacc16(acc);
        gemm_bt<256,256,8>(acc, ghA, Whh, 32);          // gate n rows at 512
        #pragma unroll
        for (int tt = 0; tt < 4; ++tt){
            int col = wave*64 + tt*16 + r16;
            float bh = bhh[512+col];
            #pragma unroll
            for (int mb = 0; mb < 4; ++mb){
                float r0 = bf2f((unsigned short)(rp[mb][tt][0] & 0xffff));
                float r1 = bf2f((unsigned short)(rp[mb][tt][0] >> 16));
                float r2 = bf2f((unsigned short)(rp[mb][tt][1] & 0xffff));
                float r3 = bf2f((unsigned short)(rp[mb][tt][1] >> 16));
                rp[mb][tt][0] = pk2(r0*(acc[mb][tt][0]+bh), r1*(acc[mb][tt][1]+bh));
                rp[mb][tt][1] = pk2(r2*(acc[mb][tt][2]+bh), r3*(acc[mb][tt][3]+bh));
            }
        }
        zacc16(acc);
        gemm_bt<256,256,8>(acc, giA, Wih, 32);
        #pragma unroll
        for (int tt = 0; tt < 4; ++tt){
            int col = wave*64 + tt*16 + r16;
            float bi = bih[512+col];
            #pragma unroll
            for (int mb = 0; mb < 4; ++mb){
                float a0 = bf2f((unsigned short)(rp[mb][tt][0] & 0xffff));
                float a1 = bf2f((unsigned short)(rp[mb][tt][0] >> 16));
                float a2 = bf2f((unsigned short)(rp[mb][tt][1] & 0xffff));
                float a3 = bf2f((unsigned short)(rp[mb][tt][1] >> 16));
                np[mb][tt][0] = pk2(tanh_(acc[mb][tt][0]+bi+a0), tanh_(acc[mb][tt][1]+bi+a1));
                np[mb][tt][1] = pk2(tanh_(acc[mb][tt][2]+bi+a2), tanh_(acc[mb][tt][3]+bi+a3));
            }
        }
    }
    {   // ---- z gate + blend ----
        facc4 acc[4][4];
        zacc16(acc);
        gemm_bt<256,256,8>(acc, giA, Wih, 16);          // gate z rows at 256
        gemm_bt<256,256,8>(acc, ghA, Whh, 16);
        #pragma unroll
        for (int tt = 0; tt < 4; ++tt){
            int col = wave*64 + tt*16 + r16;
            float bs = bih[256+col] + bhh[256+col];
            #pragma unroll
            for (int mb = 0; mb < 4; ++mb){
                #pragma unroll
                for (int k = 0; k < 4; ++k){
                    float z = sigm(acc[mb][tt][k] + bs);
                    float n = bf2f((unsigned short)(np[mb][tt][k>>1] >> ((k&1)*16)));
                    float hp = bf2f(ghA[swz(mb*16 + q4 + k, col, 256)]);
                    float h = (1.f - z)*n + z*hp;
                    if (k & 1) hpk[mb][tt][k>>1] |= ((unsigned)f2bf(h)) << 16;
                    else       hpk[mb][tt][k>>1]  = (unsigned)f2bf(h);
                }
            }
        }
    }
}

__global__ __launch_bounds__(256,2) void k_fused(
    const float* __restrict__ inputs, const float* __restrict__ h0,
    const unsigned short* __restrict__ W1p, const float* __restrict__ b1,
    const unsigned short* __restrict__ rWih, const unsigned short* __restrict__ rWhh,
    const float* __restrict__ rbih, const float* __restrict__ rbhh,
    const unsigned short* __restrict__ cWih, const unsigned short* __restrict__ cWhh,
    const float* __restrict__ cbih, const float* __restrict__ cbhh,
    const unsigned short* __restrict__ W2p, const float* __restrict__ b2,
    float* __restrict__ qout, float* __restrict__ hrnn)
{
    __shared__ unsigned short sm[64*512];      // 64 KB: input tile, then bufA|bufB
    __shared__ unsigned short NBs[64*32];      // 4 KB neighbor matrix
    __shared__ float invn[64];
    unsigned short* bufA = sm;                 // 32 KB  (x, then c)
    unsigned short* bufB = sm + 64*256;        // 32 KB  (h)
    const int base = blockIdx.x * 64;
    const int lane = threadIdx.x & 63, wave = threadIdx.x >> 6;
    const int r16 = lane & 15, q8 = (lane>>4)<<3, q4 = (lane>>4)<<2;

    // ---- stage input tile 64x512 f32->bf16 swizzled (ld=512), nt reads ----
    {
        const float* src = inputs + (size_t)base * 512;
        int t = threadIdx.x;
        #pragma unroll
        for (int it = 0; it < 16; ++it){
            int idx = it*256 + t;
            int row = idx >> 6, ch = idx & 63;
            const f32x4* s = (const f32x4*)(src + (size_t)row*512 + (ch << 3));
            f32x4 a = __builtin_nontemporal_load(s);
            f32x4 c = __builtin_nontemporal_load(s + 1);
            u32x4 o; o.x = pk2(a.x,a.y); o.y = pk2(a.z,a.w); o.z = pk2(c.x,c.y); o.w = pk2(c.z,c.w);
            *(u32x4*)(sm + row*512 + ((ch ^ (row & 7)) << 3)) = o;
        }
    }
    __syncthreads();
    // ---- neighbor matrix + 1/n into LDS (cols 260+8k of obs) ----
    if (threadIdx.x < 64){
        int row = threadIdx.x;
        int i = (base + row) & 31;
        int rx = row & 7;
        float s = 0.f;
        NBs[row*32 + i] = 0;
        #pragma unroll
        for (int k = 0; k < 31; ++k){
            unsigned short v = sm[row*512 + ((((32 + k) ^ rx) << 3) | 4)];
            s += bf2f(v);
            NBs[row*32 + k + (k >= i)] = v;
        }
        invn[row] = 1.0f / s;
    }
    // ---- x = relu(in @ W1^T + b1), into registers ----
    facc4 xacc[4][4];
    zacc16(xacc);
    gemm_bt<512,512,16>(xacc, sm, W1p, 0);
    __syncthreads();                       // input tile reads done
    // ---- x -> bufA (bf16 swizzled); h0 -> bufB ----
    #pragma unroll
    for (int tt = 0; tt < 4; ++tt){
        int col = wave*64 + tt*16 + r16;
        float bias = b1[col];
        #pragma unroll
        for (int mb = 0; mb < 4; ++mb){
            #pragma unroll
            for (int k = 0; k < 4; ++k){
                float v = fmaxf(xacc[mb][tt][k] + bias, 0.f);
                bufA[swz(mb*16 + q4 + k, col, 256)] = f2bf(v);
            }
        }
    }
    stage_f32(bufB, h0 + (size_t)base*256);
    __syncthreads();

    // ---- rnn GRU: h1 = GRU(x, h0) ----
    unsigned hpk[4][4][2];
    gru_fused(bufA, bufB, rWih, rWhh, rbih, rbhh, hpk);
    __syncthreads();                       // bufA/bufB reads done
    #pragma unroll
    for (int tt = 0; tt < 4; ++tt){
        int col = wave*64 + tt*16 + r16;
        #pragma unroll
        for (int mb = 0; mb < 4; ++mb){
            #pragma unroll
            for (int k = 0; k < 4; ++k)
                bufB[swz(mb*16 + q4 + k, col, 256)] =
                    (unsigned short)(hpk[mb][tt][k>>1] >> ((k&1)*16));
        }
    }
    __syncthreads();
    // ---- hrnn: coalesced nt f32 write from bufB ----
    {
        int t = threadIdx.x;
        #pragma unroll
        for (int it = 0; it < 8; ++it){
            int idx = it*256 + t;
            int row = idx >> 5, ch = idx & 31;
            u32x4 v = *(const u32x4*)(bufB + row*256 + ((ch ^ (row & 7)) << 3));
            float* dst = hrnn + (size_t)(base + row)*256 + (ch << 3);
            f32x4 f0, f1;
            f0.x = bf2f((unsigned short)(v.x & 0xffff)); f0.y = bf2f((unsigned short)(v.x >> 16));
            f0.z = bf2f((unsigned short)(v.y & 0xffff)); f0.w = bf2f((unsigned short)(v.y >> 16));
            f1.x = bf2f((unsigned short)(v.z & 0xffff)); f1.y = bf2f((unsigned short)(v.z >> 16));
            f1.z = bf2f((unsigned short)(v.w & 0xffff)); f1.w = bf2f((unsigned short)(v.w >> 16));
            __builtin_nontemporal_store(f0, (f32x4*)dst);
            __builtin_nontemporal_store(f1, (f32x4*)(dst + 4));
        }
    }
    // ---- 4 comm steps ----
    for (int step = 0; step < 4; ++step){
        // c = (NB @ h) * invn  -> bufA ; per 32-row group, K=32
        facc4 cacc[4][4];
        zacc16(cacc);
        frag8 a[4];
        #pragma unroll
        for (int mb = 0; mb < 4; ++mb)
            a[mb] = *(const frag8*)(NBs + (mb*16 + r16)*32 + q8);
        #pragma unroll
        for (int tt = 0; tt < 4; ++tt){
            int col = wave*64 + tt*16 + r16;
            int cc = col >> 3, c7 = col & 7;
            union { frag8 v; unsigned short u[8]; } b0l, b1l;
            #pragma unroll
            for (int j = 0; j < 8; ++j){
                int k0r = q8 + j;          // group 0: rows 0..31
                int k1r = 32 + q8 + j;     // group 1: rows 32..63
                b0l.u[j] = bufB[k0r*256 + (((cc ^ (k0r & 7)) << 3) | c7)];
                b1l.u[j] = bufB[k1r*256 + (((cc ^ (k1r & 7)) << 3) | c7)];
            }
            cacc[0][tt] = mfma16(a[0], b0l.v, cacc[0][tt]);
            cacc[1][tt] = mfma16(a[1], b0l.v, cacc[1][tt]);
            cacc[2][tt] = mfma16(a[2], b1l.v, cacc[2][tt]);
            cacc[3][tt] = mfma16(a[3], b1l.v, cacc[3][tt]);
        }
        #pragma unroll
        for (int mb = 0; mb < 4; ++mb){
            #pragma unroll
            for (int k = 0; k < 4; ++k){
                int rloc = mb*16 + q4 + k;
                float inv = invn[rloc];
                #pragma unroll
                for (int tt = 0; tt < 4; ++tt){
                    int col = wave*64 + tt*16 + r16;
                    bufA[swz(rloc, col, 256)] = f2bf(cacc[mb][tt][k] * inv);
                }
            }
        }
        __syncthreads();
        // h = GRU(h, c): gi from h (bufB), gh/blend from c (bufA)
        gru_fused(bufB, bufA, cWih, cWhh, cbih, cbhh, hpk);
        __syncthreads();
        #pragma unroll
        for (int tt = 0; tt < 4; ++tt){
            int col = wave*64 + tt*16 + r16;
            #pragma unroll
            for (int mb = 0; mb < 4; ++mb){
                #pragma unroll
                for (int k = 0; k < 4; ++k)
                    bufB[swz(mb*16 + q4 + k, col, 256)] =
                        (unsigned short)(hpk[mb][tt][k>>1] >> ((k&1)*16));
            }
        }
        __syncthreads();
    }
    // ---- q = h @ W2^T + b2 (one 16-col n-tile, wave per 16 rows) ----
    {
        facc4 acc = (facc4){0.f,0.f,0.f,0.f};
        int row = wave*16 + r16;
        const unsigned short* wl = W2p + lane*8;
        #pragma unroll
        for (int kc = 0; kc < 8; ++kc){
            int c8 = kc*4 + (q8 >> 3);
            frag8 a = *(const frag8*)(bufB + row*256 + ((c8 ^ (row & 7)) << 3));
            frag8 b = *(const frag8*)(wl + kc*512);
            acc = mfma16(a, b, acc);
        }
        float bias = b2[r16];
        #pragma unroll
        for (int k = 0; k < 4; ++k){
            int grow = base + wave*16 + q4 + k;
            __builtin_nontemporal_store(acc[k] + bias, qout + (size_t)grow*16 + r16);
        }
    }
}

extern "C" void kernel_launch(void* const* d_in, const int* in_sizes, int n_in,
                              void* d_out, int out_size, void* d_ws, size_t ws_size,
                              hipStream_t stream)
{
    const float* inputs = (const float*)d_in[0];
    const float* h0     = (const float*)d_in[1];
    const float* W1     = (const float*)d_in[2];
    const float* b1     = (const float*)d_in[3];
    const float* rWih   = (const float*)d_in[4];
    const float* rWhh   = (const float*)d_in[5];
    const float* rbih   = (const float*)d_in[6];
    const float* rbhh   = (const float*)d_in[7];
    const float* cWih   = (const float*)d_in[8];
    const float* cWhh   = (const float*)d_in[9];
    const float* cbih   = (const float*)d_in[10];
    const float* cbhh   = (const float*)d_in[11];
    const float* W2     = (const float*)d_in[12];
    const float* b2     = (const float*)d_in[13];

    float* qout = (float*)d_out;                    // 65536 x 16
    float* hrnn = qout + (size_t)65536*16;          // 65536 x 256

    // ws: bf16 weights, fragment-packed, contiguous segments
    unsigned short* wsb  = (unsigned short*)d_ws;
    unsigned short* W1p   = wsb;                    // 16384 frags
    unsigned short* rWihp = wsb + 131072;           // 24576 frags
    unsigned short* rWhhp = wsb + 327680;
    unsigned short* cWihp = wsb + 524288;
    unsigned short* cWhhp = wsb + 720896;
    unsigned short* W2p   = wsb + 917504;           // 512 frags

    dim3 blk(256);
    k_prep <<<450,  blk, 0, stream>>>(W1, rWih, rWhh, cWih, cWhh, W2, wsb);
    k_fused<<<1024, blk, 0, stream>>>(inputs, h0, W1p, b1, rWihp, rWhhp, rbih, rbhh,
                                      cWihp, cWhhp, cbih, cbhh, W2p, b2, qout, hrnn);
}